// Round 1
// baseline (18186.320 us; speedup 1.0000x reference)
//
#include <hip/hip_runtime.h>
#include <hip/hip_bf16.h>

// Problem constants (from reference): B,SE,SD,E,H,V,O
constexpr int kB  = 16;
constexpr int kSE = 128;
constexpr int kSD = 128;
constexpr int kE  = 512;
constexpr int kH  = 1024;
constexpr int kO  = 32000;

// ---------------------------------------------------------------------------
// Gather embedding rows: out[r, :] = emb[idx[r], :], r = b*S + t, row len E=512
// ---------------------------------------------------------------------------
__global__ __launch_bounds__(128) void gather_rows(
    const float* __restrict__ emb, const int* __restrict__ idx,
    float* __restrict__ out)
{
    int r = blockIdx.x;
    int t = threadIdx.x;                       // 128 threads, 128 float4 per row
    const float4* src = (const float4*)(emb + (size_t)idx[r] * kE);
    float4* dst = (float4*)(out + (size_t)r * kE);
    dst[t] = src[t];
}

// ---------------------------------------------------------------------------
// 1024x1024 transpose (for mlp1_W): out[k][j] = in[j][k]
// ---------------------------------------------------------------------------
__global__ __launch_bounds__(256) void transpose1024(
    const float* __restrict__ in, float* __restrict__ out)
{
    __shared__ float tile[32][33];
    int bx = blockIdx.x * 32, by = blockIdx.y * 32;
    int tx = threadIdx.x, ty = threadIdx.y;    // block (32,8)
    for (int i = ty; i < 32; i += 8)
        tile[i][tx] = in[(size_t)(by + i) * kH + bx + tx];
    __syncthreads();
    for (int i = ty; i < 32; i += 8)
        out[(size_t)(bx + i) * kH + by + tx] = tile[tx][i];
}

// ---------------------------------------------------------------------------
// NT GEMM: C[M x N] = A[M x K](lda) * B[N x K](ldb)^T (+ bias[N])
// BM=BN=128, BK=16, 256 threads, 8x8 per-thread tile.
// M%128==0, N%128==0, K%16==0 (holds for all uses: M=2048, N in {1024,32000},
// K in {512,1024}).
// ---------------------------------------------------------------------------
constexpr int BM = 128, BN = 128, BK = 16, LDP = 132;

__global__ __launch_bounds__(256, 2) void gemm_nt(
    const float* __restrict__ A, int lda,
    const float* __restrict__ Bmat, int ldb,
    float* __restrict__ C, int ldc,
    const float* __restrict__ bias, int K)
{
    __shared__ float As[BK][LDP];
    __shared__ float Bs[BK][LDP];

    const int bn = blockIdx.x, bm = blockIdx.y;
    const int tid = threadIdx.x;
    const int tm = tid & 15;        // 16 m-groups of 8 rows
    const int tn = tid >> 4;        // 16 n-groups of 8 cols

    const float* Ab = A    + (size_t)bm * BM * lda;
    const float* Bb = Bmat + (size_t)bn * BN * ldb;

    const int sr = tid >> 1;              // staging row 0..127
    const int sc = (tid & 1) * 8;         // staging col 0 or 8

    float acc[8][8];
    #pragma unroll
    for (int i = 0; i < 8; ++i)
        #pragma unroll
        for (int j = 0; j < 8; ++j) acc[i][j] = 0.f;

    for (int k0 = 0; k0 < K; k0 += BK) {
        const float4 a0 = *(const float4*)(Ab + (size_t)sr * lda + k0 + sc);
        const float4 a1 = *(const float4*)(Ab + (size_t)sr * lda + k0 + sc + 4);
        const float4 b0 = *(const float4*)(Bb + (size_t)sr * ldb + k0 + sc);
        const float4 b1 = *(const float4*)(Bb + (size_t)sr * ldb + k0 + sc + 4);
        __syncthreads();   // previous tile fully consumed before overwrite
        As[sc + 0][sr] = a0.x; As[sc + 1][sr] = a0.y;
        As[sc + 2][sr] = a0.z; As[sc + 3][sr] = a0.w;
        As[sc + 4][sr] = a1.x; As[sc + 5][sr] = a1.y;
        As[sc + 6][sr] = a1.z; As[sc + 7][sr] = a1.w;
        Bs[sc + 0][sr] = b0.x; Bs[sc + 1][sr] = b0.y;
        Bs[sc + 2][sr] = b0.z; Bs[sc + 3][sr] = b0.w;
        Bs[sc + 4][sr] = b1.x; Bs[sc + 5][sr] = b1.y;
        Bs[sc + 6][sr] = b1.z; Bs[sc + 7][sr] = b1.w;
        __syncthreads();

        #pragma unroll
        for (int k = 0; k < BK; ++k) {
            const float4 fa0 = *(const float4*)&As[k][tm * 8];
            const float4 fa1 = *(const float4*)&As[k][tm * 8 + 4];
            const float4 fb0 = *(const float4*)&Bs[k][tn * 8];
            const float4 fb1 = *(const float4*)&Bs[k][tn * 8 + 4];
            const float am[8] = {fa0.x, fa0.y, fa0.z, fa0.w,
                                 fa1.x, fa1.y, fa1.z, fa1.w};
            const float bb[8] = {fb0.x, fb0.y, fb0.z, fb0.w,
                                 fb1.x, fb1.y, fb1.z, fb1.w};
            #pragma unroll
            for (int i = 0; i < 8; ++i)
                #pragma unroll
                for (int j = 0; j < 8; ++j)
                    acc[i][j] += am[i] * bb[j];
        }
    }

    float bv[8];
    if (bias) {
        const float4 t0 = *(const float4*)&bias[bn * BN + tn * 8];
        const float4 t1 = *(const float4*)&bias[bn * BN + tn * 8 + 4];
        bv[0] = t0.x; bv[1] = t0.y; bv[2] = t0.z; bv[3] = t0.w;
        bv[4] = t1.x; bv[5] = t1.y; bv[6] = t1.z; bv[7] = t1.w;
    } else {
        #pragma unroll
        for (int j = 0; j < 8; ++j) bv[j] = 0.f;
    }
    #pragma unroll
    for (int i = 0; i < 8; ++i) {
        const size_t row = (size_t)(bm * BM + tm * 8 + i);
        float* cp = C + row * (size_t)ldc + bn * BN + tn * 8;
        float4 o0 = {acc[i][0] + bv[0], acc[i][1] + bv[1],
                     acc[i][2] + bv[2], acc[i][3] + bv[3]};
        float4 o1 = {acc[i][4] + bv[4], acc[i][5] + bv[5],
                     acc[i][6] + bv[6], acc[i][7] + bv[7]};
        *(float4*)cp = o0;
        *(float4*)(cp + 4) = o1;
    }
}

// ---------------------------------------------------------------------------
// cb[r] = dot(M[r, 0:H], v)  — one wave per row
// ---------------------------------------------------------------------------
__global__ __launch_bounds__(256) void dot_bias(
    const float* __restrict__ Mrows, const float* __restrict__ v,
    float* __restrict__ out)
{
    int w = (blockIdx.x * blockDim.x + threadIdx.x) >> 6;
    int lane = threadIdx.x & 63;
    const float* row = Mrows + (size_t)w * kH;
    float s = 0.f;
    for (int k = lane; k < kH; k += 64) s += row[k] * v[k];
    #pragma unroll
    for (int off = 32; off > 0; off >>= 1) s += __shfl_xor(s, off);
    if (lane == 0) out[w] = s;
}

// ---------------------------------------------------------------------------
// Encoder step: h_out[b,j] = tanh(X[(b*SE+t), j] + dot(h_in[b,:], Whh[j,:]))
// grid (16 j-tiles, 16 b), block 64
// ---------------------------------------------------------------------------
__global__ __launch_bounds__(64) void enc_step(
    const float* __restrict__ X, const float* __restrict__ hin,
    const float* __restrict__ Whh, float* __restrict__ hout,
    float* __restrict__ hist, int t)
{
    const int b = blockIdx.y;
    const int j = blockIdx.x * 64 + threadIdx.x;
    const float* hr = hin + b * kH;
    const float* wr = Whh + (size_t)j * kH;
    float a0 = 0, a1 = 0, a2 = 0, a3 = 0, a4 = 0, a5 = 0, a6 = 0, a7 = 0;
    #pragma unroll 4
    for (int k = 0; k < kH; k += 8) {
        const float4 h0 = *(const float4*)(hr + k);
        const float4 h1 = *(const float4*)(hr + k + 4);
        const float4 w0 = *(const float4*)(wr + k);
        const float4 w1 = *(const float4*)(wr + k + 4);
        a0 += h0.x * w0.x; a1 += h0.y * w0.y; a2 += h0.z * w0.z; a3 += h0.w * w0.w;
        a4 += h1.x * w1.x; a5 += h1.y * w1.y; a6 += h1.z * w1.z; a7 += h1.w * w1.w;
    }
    const float acc = X[((size_t)b * kSE + t) * kH + j] +
                      ((a0 + a1) + (a2 + a3)) + ((a4 + a5) + (a6 + a7));
    const float r = tanhf(acc);
    hout[b * kH + j] = r;
    hist[((size_t)b * kSE + t) * kH + j] = r;
}

// ---------------------------------------------------------------------------
// Decoder attention step (one block per batch element b):
//   scores[s] = dot(Aw[b*SE+s,:], h[b,:]) + cb[b*SE+s]
//   attn = softmax(scores); ctx[b,j] = sum_s attn[s]*EH[b*SE+s, j]
// ---------------------------------------------------------------------------
__global__ __launch_bounds__(256) void attn_step(
    const float* __restrict__ Aw, const float* __restrict__ cb,
    const float* __restrict__ hin, const float* __restrict__ EH,
    float* __restrict__ ctx)
{
    __shared__ float hl[kH];
    __shared__ float sc[kSE];
    const int b = blockIdx.x;
    const int tid = threadIdx.x;
    const int lane = tid & 63;
    const int w = tid >> 6;

    for (int k = tid; k < kH; k += 256) hl[k] = hin[b * kH + k];
    __syncthreads();

    for (int s = w; s < kSE; s += 4) {
        const float* ar = Aw + ((size_t)b * kSE + s) * kH;
        float p = 0.f;
        for (int k = lane; k < kH; k += 64) p += ar[k] * hl[k];
        #pragma unroll
        for (int off = 32; off > 0; off >>= 1) p += __shfl_xor(p, off);
        if (lane == 0) sc[s] = p + cb[b * kSE + s];
    }
    __syncthreads();

    if (w == 0) {   // wave 0: softmax over 128 scores
        float v0 = sc[lane], v1 = sc[lane + 64];
        float m = fmaxf(v0, v1);
        #pragma unroll
        for (int off = 32; off > 0; off >>= 1) m = fmaxf(m, __shfl_xor(m, off));
        const float e0 = expf(v0 - m), e1 = expf(v1 - m);
        float s = e0 + e1;
        #pragma unroll
        for (int off = 32; off > 0; off >>= 1) s += __shfl_xor(s, off);
        const float inv = 1.f / s;
        sc[lane] = e0 * inv;
        sc[lane + 64] = e1 * inv;
    }
    __syncthreads();

    for (int j = tid; j < kH; j += 256) {
        float a0 = 0.f, a1 = 0.f;
        #pragma unroll 2
        for (int s = 0; s < kSE; s += 2) {
            a0 += sc[s]     * EH[((size_t)b * kSE + s)     * kH + j];
            a1 += sc[s + 1] * EH[((size_t)b * kSE + s + 1) * kH + j];
        }
        ctx[b * kH + j] = a0 + a1;
    }
}

// ---------------------------------------------------------------------------
// Decoder hidden step:
// h_out[b,j] = tanh(X[(b*SD+t),j] + dot(ctx[b,:],Wih[j,E:]) + dot(h[b,:],Whh[j,:]))
// ---------------------------------------------------------------------------
__global__ __launch_bounds__(64) void dec_hstep(
    const float* __restrict__ X, const float* __restrict__ ctx,
    const float* __restrict__ Wih, const float* __restrict__ Whh,
    const float* __restrict__ hin, float* __restrict__ hout,
    float* __restrict__ Hs, int t)
{
    const int b = blockIdx.y;
    const int j = blockIdx.x * 64 + threadIdx.x;
    const float* cr = ctx + b * kH;
    const float* hr = hin + b * kH;
    const float* wc = Wih + (size_t)j * (kE + kH) + kE;   // ctx block of dec_Wih
    const float* wh = Whh + (size_t)j * kH;
    float a0 = 0, a1 = 0, a2 = 0, a3 = 0, a4 = 0, a5 = 0, a6 = 0, a7 = 0;
    #pragma unroll 4
    for (int k = 0; k < kH; k += 4) {
        const float4 cv = *(const float4*)(cr + k);
        const float4 wv = *(const float4*)(wc + k);
        const float4 hv = *(const float4*)(hr + k);
        const float4 uv = *(const float4*)(wh + k);
        a0 += cv.x * wv.x; a1 += cv.y * wv.y; a2 += cv.z * wv.z; a3 += cv.w * wv.w;
        a4 += hv.x * uv.x; a5 += hv.y * uv.y; a6 += hv.z * uv.z; a7 += hv.w * uv.w;
    }
    const float acc = X[((size_t)b * kSD + t) * kH + j] +
                      ((a0 + a1) + (a2 + a3)) + ((a4 + a5) + (a6 + a7));
    const float r = tanhf(acc);
    hout[b * kH + j] = r;
    Hs[((size_t)b * kSD + t) * kH + j] = r;
}

// ---------------------------------------------------------------------------
extern "C" void kernel_launch(void* const* d_in, const int* in_sizes, int n_in,
                              void* d_out, int out_size, void* d_ws, size_t ws_size,
                              hipStream_t stream)
{
    const int*   enc_x   = (const int*)  d_in[0];
    const int*   dec_y   = (const int*)  d_in[1];
    const float* state0  = (const float*)d_in[2];
    const float* emb     = (const float*)d_in[3];
    const float* enc_Wih = (const float*)d_in[4];
    const float* enc_Whh = (const float*)d_in[5];
    const float* enc_b   = (const float*)d_in[6];
    const float* mlp1_W  = (const float*)d_in[7];
    const float* mlp1_b  = (const float*)d_in[8];
    const float* dec_Wih = (const float*)d_in[9];
    const float* dec_Whh = (const float*)d_in[10];
    const float* dec_b   = (const float*)d_in[11];
    const float* mlp2_W  = (const float*)d_in[12];
    const float* mlp2_b  = (const float*)d_in[13];
    float* out = (float*)d_out;

    // Workspace layout (floats)
    float* ws = (float*)d_ws;
    size_t off = 0;
    const int R = kB * kSE;                       // 2048 rows (b*128+t)
    float* EncEmb = ws + off; off += (size_t)R * kE;   // 2048 x 512
    float* DecEmb = ws + off; off += (size_t)R * kE;   // 2048 x 512
    float* Xenc   = ws + off; off += (size_t)R * kH;   // 2048 x 1024
    float* Xdec   = ws + off; off += (size_t)R * kH;   // 2048 x 1024
    float* EH     = ws + off; off += (size_t)R * kH;   // encoder hiddens
    float* Aw     = ws + off; off += (size_t)R * kH;   // EH @ mlp1_W
    float* W1T    = ws + off; off += (size_t)kH * kH;  // mlp1_W transposed
    float* cbv    = ws + off; off += R;                // EH @ mlp1_b
    float* h0     = ws + off; off += kB * kH;
    float* h1     = ws + off; off += kB * kH;
    float* ctx    = ws + off; off += kB * kH;
    float* Hs     = ws + off; off += (size_t)R * kH;   // decoder hiddens
    float* hbuf[2] = {h0, h1};

    // 1) Embedding gathers
    gather_rows<<<R, 128, 0, stream>>>(emb, enc_x, EncEmb);
    gather_rows<<<R, 128, 0, stream>>>(emb, dec_y, DecEmb);

    // 2) Input projections for all timesteps (hoisted out of the scans)
    gemm_nt<<<dim3(kH / BN, R / BM), 256, 0, stream>>>(
        EncEmb, kE, enc_Wih, kE, Xenc, kH, enc_b, kE);
    gemm_nt<<<dim3(kH / BN, R / BM), 256, 0, stream>>>(
        DecEmb, kE, dec_Wih, kE + kH, Xdec, kH, dec_b, kE);

    // 3) h0 = state0
    hipMemcpyAsync(h0, state0, (size_t)kB * kH * sizeof(float),
                   hipMemcpyDeviceToDevice, stream);

    // 4) Encoder scan
    for (int t = 0; t < kSE; ++t) {
        enc_step<<<dim3(kH / 64, kB), 64, 0, stream>>>(
            Xenc, hbuf[t & 1], enc_Whh, hbuf[(t + 1) & 1], EH, t);
    }
    // encoder final state ends in hbuf[0] (128 steps, even)

    // 5) Attention precompute: Aw = EH @ mlp1_W  (needs W1^T for NT gemm),
    //    cbv = EH @ mlp1_b
    transpose1024<<<dim3(32, 32), dim3(32, 8), 0, stream>>>(mlp1_W, W1T);
    gemm_nt<<<dim3(kH / BN, R / BM), 256, 0, stream>>>(
        EH, kH, W1T, kH, Aw, kH, nullptr, kH);
    dot_bias<<<R / 4, 256, 0, stream>>>(EH, mlp1_b, cbv);

    // 6) Decoder scan
    for (int t = 0; t < kSD; ++t) {
        attn_step<<<kB, 256, 0, stream>>>(Aw, cbv, hbuf[t & 1], EH, ctx);
        dec_hstep<<<dim3(kH / 64, kB), 64, 0, stream>>>(
            Xdec, ctx, dec_Wih, dec_Whh, hbuf[t & 1], hbuf[(t + 1) & 1], Hs, t);
    }

    // 7) Batched output projection: out = Hs @ mlp2_W^T + mlp2_b
    gemm_nt<<<dim3(kO / BN, R / BM), 256, 0, stream>>>(
        Hs, kH, mlp2_W, kH, out, kO, mlp2_b, kH);
}